// Round 9
// baseline (7503.461 us; speedup 1.0000x reference)
//
#include <hip/hip_runtime.h>
#include <math.h>

// JordanRNN B=128,T=2048,I=128,H=256,O=64.
// R16: DUAL-COLUMN ILP INTERLEAVE over the proven R13 protocol.
// 16 WGs x 256 thr: WG = quarter q of columns {2p, 2p+1}. The two columns
// are INDEPENDENT recurrences; interleaving their phases in one WG covers
// the ~1-RT MALL exposure per step with the other chain's compute. Weights
// depend only on q -> the ~200 weight VGPRs are SHARED between chains;
// only accumulators/hprev/x regs duplicate (~+110 VGPR, 1 wave/EU budget
// 512). sc0 is permanently abandoned (3/3 container wedges: R8/R9/R15);
// transport = sc1/MALL packets, validation byte-identical to R13 (16B
// {d0,d1,epoch,d0^d1^epoch}, tear-proof, eager register publish at C).
// vmcnt accounting (all in-loop VMEM is inline asm): per-step issue order
// [ld_xA(2) ld_xB(2) | stA(1) stB(1) | pktA(3) pktB(3)] -> at validate,
// vmcnt(3) retires everything through pktA (9 oldest of 12), vmcnt(0)
// retires pktB. Retry loops drain to vmcnt(0) (subsumes counts safely).
// Stale-reg hazard is benign: un-landed packet regs hold last step's
// accepted packet (epoch t-2 < t-1 -> fails check -> retry reloads).
// ws: pay[2 parity][8 col][16 slot][64 lane]x16B = 262144 B (memset 0 =
// epoch 0 + h(0)=0, XOR-valid).

#define TSTEPS 2048
#define ISZ 128

typedef _Float16 half8 __attribute__((ext_vector_type(8)));
typedef float f32x4 __attribute__((ext_vector_type(4)));
typedef unsigned int u32;
typedef unsigned int u32x4 __attribute__((ext_vector_type(4)));
typedef unsigned long long u64;

__device__ __forceinline__ f32x4 mfma16(half8 a, half8 b, f32x4 c) {
  return __builtin_amdgcn_mfma_f32_16x16x32_f16(a, b, c, 0, 0, 0);
}
__device__ __forceinline__ float sigm(float x) {
  return __builtin_amdgcn_rcpf(1.f + __expf(-x));
}
__device__ __forceinline__ float tanh_fast(float x) {
  return 1.f - 2.f * __builtin_amdgcn_rcpf(1.f + __expf(2.f * x));
}
__device__ __forceinline__ float asf(u32 u) {
  union { u32 v; float f; } c; c.v = u; return c.f;
}

// ---- MALL packet ops (sc1 = device-coherent, bypasses non-coherent L2s)
__device__ __forceinline__ void st_pkt(void* p, u32x4 v) {
  asm volatile("global_store_dwordx4 %0, %1, off sc1" :: "v"(p), "v"(v) : "memory");
}
__device__ __forceinline__ void ld_pkt3_issue(const void* p1, const void* p2,
                                              const void* p3, u32x4& r1, u32x4& r2,
                                              u32x4& r3) {
  asm volatile("global_load_dwordx4 %0, %3, off sc1\n\t"
               "global_load_dwordx4 %1, %4, off sc1\n\t"
               "global_load_dwordx4 %2, %5, off sc1"
               : "=&v"(r1), "=&v"(r2), "=&v"(r3)
               : "v"(p1), "v"(p2), "v"(p3) : "memory");
}
__device__ __forceinline__ void ld_pkt3_wait(const void* p1, const void* p2,
                                             const void* p3, u32x4& r1, u32x4& r2,
                                             u32x4& r3) {
  asm volatile("global_load_dwordx4 %0, %3, off sc1\n\t"
               "global_load_dwordx4 %1, %4, off sc1\n\t"
               "global_load_dwordx4 %2, %5, off sc1\n\t"
               "s_waitcnt vmcnt(0)"
               : "=&v"(r1), "=&v"(r2), "=&v"(r3)
               : "v"(p1), "v"(p2), "v"(p3) : "memory");
}
// x prefetch: 2x16B plain asm loads (keeps compiler out of vmcnt counting)
__device__ __forceinline__ void ld_x2(const float* p, u32x4& x0, u32x4& x1) {
  asm volatile("global_load_dwordx4 %0, %2, off\n\t"
               "global_load_dwordx4 %1, %3, off"
               : "=&v"(x0), "=&v"(x1)
               : "v"(p), "v"(p + 4) : "memory");
}
#define PKT_OK(r, tgt) (((r)[2] >= (tgt)) && (((r)[0] ^ (r)[1] ^ (r)[2]) == (r)[3]))
#define SB() __builtin_amdgcn_sched_barrier(0)

__global__ __attribute__((amdgpu_flat_work_group_size(256, 256),
                          amdgpu_waves_per_eu(1, 1)))
void jordan_rnn(const float* __restrict__ xg, const float* __restrict__ w_ih,
                const float* __restrict__ w_hh, const float* __restrict__ b_ih,
                const float* __restrict__ b_hh, const float* __restrict__ fc_w,
                const float* __restrict__ fc_b, float* __restrict__ out,
                unsigned char* __restrict__ ws)
{
  const int tid  = threadIdx.x;
  const int lane = tid & 63;
  const int wv   = tid >> 6;          // wave 0..3
  const int n    = lane & 15;
  const int quad = lane >> 4;
  const int pr   = blockIdx.x & 3;    // column pair 0..3
  const int q    = blockIdx.x >> 2;   // hidden quarter 0..3
  const int colA = pr * 2, colB = pr * 2 + 1;
  const int u0   = q * 64 + wv * 16;  // this wave's unit slice
  const int b0A  = colA * 16, b0B = colB * 16;

  unsigned char* pay = ws;

  // act[chain]: cols 0..127 = x, 128..191 = y(t-1), 192..447 = h
  __shared__ _Float16 act[2][16][456];
  {
    u32* za = (u32*)&act[0][0][0];
    for (int i = tid; i < 7296; i += 256) za[i] = 0u;
  }

  // ---- register-resident weights (depend only on q -> shared by chains)
  half8 wr[14], wz[14], win[6], whn[8], wfc[8];
  {
    const int kq = quad * 8;
    const int ur = u0 + n, uz = 256 + u0 + n, un = 512 + u0 + n;
#pragma unroll
    for (int kk = 0; kk < 6; ++kk) {            // k 0..191: w_ih (x|y)
      const float* prr = w_ih + ur * 192 + kk * 32 + kq;
      const float* pz = w_ih + uz * 192 + kk * 32 + kq;
      const float* pn = w_ih + un * 192 + kk * 32 + kq;
#pragma unroll
      for (int j = 0; j < 8; ++j) {
        wr[kk][j] = (_Float16)prr[j]; wz[kk][j] = (_Float16)pz[j]; win[kk][j] = (_Float16)pn[j];
      }
    }
#pragma unroll
    for (int kk = 0; kk < 8; ++kk) {            // k 192..447: w_hh
      const float* prr = w_hh + ur * 256 + kk * 32 + kq;
      const float* pz = w_hh + uz * 256 + kk * 32 + kq;
      const float* pn = w_hh + un * 256 + kk * 32 + kq;
#pragma unroll
      for (int j = 0; j < 8; ++j) {
        wr[6 + kk][j] = (_Float16)prr[j]; wz[6 + kk][j] = (_Float16)pz[j]; whn[kk][j] = (_Float16)pn[j];
      }
    }
#pragma unroll
    for (int kk = 0; kk < 8; ++kk) {            // fc: rows wv*16+n, all K
      const float* pf = fc_w + (wv * 16 + n) * 256 + kk * 32 + kq;
#pragma unroll
      for (int j = 0; j < 8; ++j) wfc[kk][j] = (_Float16)pf[j];
    }
  }
  const float br   = b_ih[u0 + n] + b_hh[u0 + n];
  const float bz   = b_ih[256 + u0 + n] + b_hh[256 + u0 + n];
  const float bin_ = b_ih[512 + u0 + n];
  const float bhn  = b_hh[512 + u0 + n];
  const float fcb  = fc_b[wv * 16 + n];

  float hpA[4] = {0.f, 0.f, 0.f, 0.f};
  float hpB[4] = {0.f, 0.f, 0.f, 0.f};

  // roles
  const int xr = tid >> 4, xc = tid & 15;       // x stage: row, 8 floats at xc*8
  const int sblk = tid >> 6, srem = tid & 63;   // partner-quarter stage decode
  const int cr = (srem >> 4) * 4;               // column-packet: base row
  const int cc = srem & 15;                     //   col within producer wave slice
  const int ok0 = 6 + 2 * q;                    // own-quarter gate frag idx
  const int fk0 = 2 * q;                        // own-quarter fc frag idx
  const int q1 = (q + 1) & 3, q2 = (q + 2) & 3, q3 = (q + 3) & 3;

  // packet addressing: [parity 131072][col 16384][(q*4+wv) 1024][lane 16]
  unsigned char* cbA0 = pay + (size_t)colA * 16384;
  unsigned char* cbA1 = cbA0 + 131072;
  unsigned char* cbB0 = pay + (size_t)colB * 16384;
  unsigned char* cbB1 = cbB0 + 131072;
  const int poff = (q * 4 + wv) * 1024 + lane * 16;
  const int off1 = (q1 * 4 + sblk) * 1024 + srem * 16;
  const int off2 = (q2 * 4 + sblk) * 1024 + srem * 16;
  const int off3 = (q3 * 4 + sblk) * 1024 + srem * 16;

  const float* xbA = xg + (size_t)(b0A + xr) * TSTEPS * ISZ + xc * 8;
  const float* xbB = xg + (size_t)(b0B + xr) * TSTEPS * ISZ + xc * 8;
  u32x4 xwA0, xwA1, xwB0, xwB1;

  // prologue: stage x(0) both chains; asm-prefetch x(1) both
  {
    float4 a = *(const float4*)xbA, b = *(const float4*)(xbA + 4);
    union { _Float16 h[8]; uint4 u; } pk;
    pk.h[0]=(_Float16)a.x; pk.h[1]=(_Float16)a.y; pk.h[2]=(_Float16)a.z; pk.h[3]=(_Float16)a.w;
    pk.h[4]=(_Float16)b.x; pk.h[5]=(_Float16)b.y; pk.h[6]=(_Float16)b.z; pk.h[7]=(_Float16)b.w;
    *(uint4*)&act[0][xr][xc * 8] = pk.u;
    float4 c = *(const float4*)xbB, d = *(const float4*)(xbB + 4);
    pk.h[0]=(_Float16)c.x; pk.h[1]=(_Float16)c.y; pk.h[2]=(_Float16)c.z; pk.h[3]=(_Float16)c.w;
    pk.h[4]=(_Float16)d.x; pk.h[5]=(_Float16)d.y; pk.h[6]=(_Float16)d.z; pk.h[7]=(_Float16)d.w;
    *(uint4*)&act[1][xr][xc * 8] = pk.u;
    ld_x2(xbA + ISZ, xwA0, xwA1);
    ld_x2(xbB + ISZ, xwB0, xwB1);
  }
  __syncthreads();

  for (int t = 1; t <= TSTEPS; ++t) {
    const u32 tgt = (u32)(t - 1);
    unsigned char* cbA = ((t - 1) & 1) ? cbA1 : cbA0;
    unsigned char* cbB = ((t - 1) & 1) ? cbB1 : cbB0;

    // ---- pre-issue both chains' partner packet loads (RTs fly together)
    u32x4 a1, a2, a3, b1, b2, b3;
    ld_pkt3_issue(cbA + off1, cbA + off2, cbA + off3, a1, a2, a3);
    ld_pkt3_issue(cbB + off1, cbB + off2, cbB + off3, b1, b2, b3);

    // ---- A(colA): partner-independent pre-MFMAs
    f32x4 RA = {0,0,0,0}, ZA = {0,0,0,0}, NA = {0,0,0,0}, HA = {0,0,0,0}, YA = {0,0,0,0};
    f32x4 RB = {0,0,0,0}, ZB = {0,0,0,0}, NB = {0,0,0,0}, HB = {0,0,0,0}, YB = {0,0,0,0};
#pragma unroll
    for (int kk = 0; kk < 4; ++kk) {
      half8 af = *(const half8*)&act[0][n][kk * 32 + quad * 8];
      RA = mfma16(af, wr[kk], RA); ZA = mfma16(af, wz[kk], ZA); NA = mfma16(af, win[kk], NA);
    }
#pragma unroll
    for (int kk = 0; kk < 2; ++kk) {
      half8 af = *(const half8*)&act[0][n][(ok0 + kk) * 32 + quad * 8];
      RA = mfma16(af, wr[ok0 + kk], RA); ZA = mfma16(af, wz[ok0 + kk], ZA);
      HA = mfma16(af, whn[ok0 - 6 + kk], HA);
    }
#pragma unroll
    for (int kk = 0; kk < 2; ++kk) {
      half8 af = *(const half8*)&act[0][n][192 + (fk0 + kk) * 32 + quad * 8];
      YA = mfma16(af, wfc[fk0 + kk], YA);
    }
    // ---- A(colB)
#pragma unroll
    for (int kk = 0; kk < 4; ++kk) {
      half8 af = *(const half8*)&act[1][n][kk * 32 + quad * 8];
      RB = mfma16(af, wr[kk], RB); ZB = mfma16(af, wz[kk], ZB); NB = mfma16(af, win[kk], NB);
    }
#pragma unroll
    for (int kk = 0; kk < 2; ++kk) {
      half8 af = *(const half8*)&act[1][n][(ok0 + kk) * 32 + quad * 8];
      RB = mfma16(af, wr[ok0 + kk], RB); ZB = mfma16(af, wz[ok0 + kk], ZB);
      HB = mfma16(af, whn[ok0 - 6 + kk], HB);
    }
#pragma unroll
    for (int kk = 0; kk < 2; ++kk) {
      half8 af = *(const half8*)&act[1][n][192 + (fk0 + kk) * 32 + quad * 8];
      YB = mfma16(af, wfc[fk0 + kk], YB);
    }

    // ---- validate A (vmcnt(3): retires xA,xB,stA,stB,pktA; pktB in flight)
    SB();
    asm volatile("s_waitcnt vmcnt(3)" : "+v"(a1), "+v"(a2), "+v"(a3) :: "memory");
    SB();
    {
      int ok = PKT_OK(a1, tgt) && PKT_OK(a2, tgt) && PKT_OK(a3, tgt);
      while (!__all(ok)) {
        __builtin_amdgcn_s_sleep(1);
        ld_pkt3_wait(cbA + off1, cbA + off2, cbA + off3, a1, a2, a3);
        ok = PKT_OK(a1, tgt) && PKT_OK(a2, tgt) && PKT_OK(a3, tgt);
      }
    }
    {
      union { u64 u; _Float16 h[4]; } w1, w2, w3;
      w1.u = ((u64)a1[1] << 32) | a1[0];
      w2.u = ((u64)a2[1] << 32) | a2[0];
      w3.u = ((u64)a3[1] << 32) | a3[0];
#pragma unroll
      for (int r = 0; r < 4; ++r) {
        act[0][cr + r][192 + q1 * 64 + sblk * 16 + cc] = w1.h[r];
        act[0][cr + r][192 + q2 * 64 + sblk * 16 + cc] = w2.h[r];
        act[0][cr + r][192 + q3 * 64 + sblk * 16 + cc] = w3.h[r];
      }
    }
    // ---- validate B
    SB();
    asm volatile("s_waitcnt vmcnt(0)" : "+v"(b1), "+v"(b2), "+v"(b3) :: "memory");
    SB();
    {
      int ok = PKT_OK(b1, tgt) && PKT_OK(b2, tgt) && PKT_OK(b3, tgt);
      while (!__all(ok)) {
        __builtin_amdgcn_s_sleep(1);
        ld_pkt3_wait(cbB + off1, cbB + off2, cbB + off3, b1, b2, b3);
        ok = PKT_OK(b1, tgt) && PKT_OK(b2, tgt) && PKT_OK(b3, tgt);
      }
    }
    {
      union { u64 u; _Float16 h[4]; } w1, w2, w3;
      w1.u = ((u64)b1[1] << 32) | b1[0];
      w2.u = ((u64)b2[1] << 32) | b2[0];
      w3.u = ((u64)b3[1] << 32) | b3[0];
#pragma unroll
      for (int r = 0; r < 4; ++r) {
        act[1][cr + r][192 + q1 * 64 + sblk * 16 + cc] = w1.h[r];
        act[1][cr + r][192 + q2 * 64 + sblk * 16 + cc] = w2.h[r];
        act[1][cr + r][192 + q3 * 64 + sblk * 16 + cc] = w3.h[r];
      }
    }
    __syncthreads();  // S1: both chains' h(t-1) staged

    // ---- B(colA): partner-h gates + partner fc; y(t-1); x stage+prefetch
#pragma unroll
    for (int kk = 6; kk < 14; ++kk) {
      if (kk == ok0 || kk == ok0 + 1) continue;
      half8 af = *(const half8*)&act[0][n][kk * 32 + quad * 8];
      RA = mfma16(af, wr[kk], RA); ZA = mfma16(af, wz[kk], ZA);
      HA = mfma16(af, whn[kk - 6], HA);
    }
#pragma unroll
    for (int kk = 0; kk < 8; ++kk) {
      if (kk == fk0 || kk == fk0 + 1) continue;
      half8 af = *(const half8*)&act[0][n][192 + kk * 32 + quad * 8];
      YA = mfma16(af, wfc[kk], YA);
    }
    if (t > 1) {
#pragma unroll
      for (int r = 0; r < 4; ++r)
        act[0][quad * 4 + r][128 + wv * 16 + n] = (_Float16)tanh_fast(YA[r] + fcb);
    }
    {
      union { _Float16 h[8]; uint4 u; } pk;
      pk.h[0]=(_Float16)asf(xwA0[0]); pk.h[1]=(_Float16)asf(xwA0[1]);
      pk.h[2]=(_Float16)asf(xwA0[2]); pk.h[3]=(_Float16)asf(xwA0[3]);
      pk.h[4]=(_Float16)asf(xwA1[0]); pk.h[5]=(_Float16)asf(xwA1[1]);
      pk.h[6]=(_Float16)asf(xwA1[2]); pk.h[7]=(_Float16)asf(xwA1[3]);
      *(uint4*)&act[0][xr][xc * 8] = pk.u;
      const size_t ts = (t + 1 < TSTEPS) ? (size_t)(t + 1) : (size_t)(TSTEPS - 1);
      ld_x2(xbA + ts * ISZ, xwA0, xwA1);
    }
    // ---- B(colB)
#pragma unroll
    for (int kk = 6; kk < 14; ++kk) {
      if (kk == ok0 || kk == ok0 + 1) continue;
      half8 af = *(const half8*)&act[1][n][kk * 32 + quad * 8];
      RB = mfma16(af, wr[kk], RB); ZB = mfma16(af, wz[kk], ZB);
      HB = mfma16(af, whn[kk - 6], HB);
    }
#pragma unroll
    for (int kk = 0; kk < 8; ++kk) {
      if (kk == fk0 || kk == fk0 + 1) continue;
      half8 af = *(const half8*)&act[1][n][192 + kk * 32 + quad * 8];
      YB = mfma16(af, wfc[kk], YB);
    }
    if (t > 1) {
#pragma unroll
      for (int r = 0; r < 4; ++r)
        act[1][quad * 4 + r][128 + wv * 16 + n] = (_Float16)tanh_fast(YB[r] + fcb);
    }
    {
      union { _Float16 h[8]; uint4 u; } pk;
      pk.h[0]=(_Float16)asf(xwB0[0]); pk.h[1]=(_Float16)asf(xwB0[1]);
      pk.h[2]=(_Float16)asf(xwB0[2]); pk.h[3]=(_Float16)asf(xwB0[3]);
      pk.h[4]=(_Float16)asf(xwB1[0]); pk.h[5]=(_Float16)asf(xwB1[1]);
      pk.h[6]=(_Float16)asf(xwB1[2]); pk.h[7]=(_Float16)asf(xwB1[3]);
      *(uint4*)&act[1][xr][xc * 8] = pk.u;
      const size_t ts = (t + 1 < TSTEPS) ? (size_t)(t + 1) : (size_t)(TSTEPS - 1);
      ld_x2(xbB + ts * ISZ, xwB0, xwB1);
    }
    __syncthreads();  // S2: y(t-1) + x(t) staged, both chains

    // ---- C(colA): y gates, gating, eager publish, h-write
#pragma unroll
    for (int kk = 4; kk < 6; ++kk) {
      half8 af = *(const half8*)&act[0][n][kk * 32 + quad * 8];
      RA = mfma16(af, wr[kk], RA); ZA = mfma16(af, wz[kk], ZA); NA = mfma16(af, win[kk], NA);
    }
    {
      union { _Float16 h[4]; u64 u; } ph;
#pragma unroll
      for (int r = 0; r < 4; ++r) {
        float rg = sigm(RA[r] + br);
        float zg = sigm(ZA[r] + bz);
        float nn = tanh_fast(NA[r] + bin_ + rg * (HA[r] + bhn));
        float hv = (1.f - zg) * nn + zg * hpA[r];
        hpA[r] = hv;
        ph.h[r] = (_Float16)hv;
      }
      unsigned char* cbw = (t & 1) ? cbA1 : cbA0;
      u32x4 pkt;
      pkt[0] = (u32)ph.u; pkt[1] = (u32)(ph.u >> 32); pkt[2] = (u32)t;
      pkt[3] = pkt[0] ^ pkt[1] ^ pkt[2];
      st_pkt(cbw + poff, pkt);
#pragma unroll
      for (int r = 0; r < 4; ++r)
        act[0][quad * 4 + r][192 + u0 + n] = ph.h[r];
    }
    // ---- C(colB)
#pragma unroll
    for (int kk = 4; kk < 6; ++kk) {
      half8 af = *(const half8*)&act[1][n][kk * 32 + quad * 8];
      RB = mfma16(af, wr[kk], RB); ZB = mfma16(af, wz[kk], ZB); NB = mfma16(af, win[kk], NB);
    }
    {
      union { _Float16 h[4]; u64 u; } ph;
#pragma unroll
      for (int r = 0; r < 4; ++r) {
        float rg = sigm(RB[r] + br);
        float zg = sigm(ZB[r] + bz);
        float nn = tanh_fast(NB[r] + bin_ + rg * (HB[r] + bhn));
        float hv = (1.f - zg) * nn + zg * hpB[r];
        hpB[r] = hv;
        ph.h[r] = (_Float16)hv;
      }
      unsigned char* cbw = (t & 1) ? cbB1 : cbB0;
      u32x4 pkt;
      pkt[0] = (u32)ph.u; pkt[1] = (u32)(ph.u >> 32); pkt[2] = (u32)t;
      pkt[3] = pkt[0] ^ pkt[1] ^ pkt[2];
      st_pkt(cbw + poff, pkt);
#pragma unroll
      for (int r = 0; r < 4; ++r)
        act[1][quad * 4 + r][192 + u0 + n] = ph.h[r];
    }
    __syncthreads();  // S3: own h(t) quarter complete, both chains
  }

  // ---- epilogue: only q==0 WGs produce out (both columns)
  if (q == 0) {
    const u32 tgt = (u32)TSTEPS;
    unsigned char* cbA = (TSTEPS & 1) ? cbA1 : cbA0;
    unsigned char* cbB = (TSTEPS & 1) ? cbB1 : cbB0;

    u32x4 a1, a2, a3, b1, b2, b3;
    ld_pkt3_issue(cbA + off1, cbA + off2, cbA + off3, a1, a2, a3);
    ld_pkt3_issue(cbB + off1, cbB + off2, cbB + off3, b1, b2, b3);

    f32x4 YA = {0,0,0,0}, YB = {0,0,0,0};
#pragma unroll
    for (int kk = 0; kk < 2; ++kk) {
      half8 af = *(const half8*)&act[0][n][192 + (fk0 + kk) * 32 + quad * 8];
      YA = mfma16(af, wfc[fk0 + kk], YA);
    }
#pragma unroll
    for (int kk = 0; kk < 2; ++kk) {
      half8 af = *(const half8*)&act[1][n][192 + (fk0 + kk) * 32 + quad * 8];
      YB = mfma16(af, wfc[fk0 + kk], YB);
    }

    SB();
    asm volatile("s_waitcnt vmcnt(3)" : "+v"(a1), "+v"(a2), "+v"(a3) :: "memory");
    SB();
    {
      int ok = PKT_OK(a1, tgt) && PKT_OK(a2, tgt) && PKT_OK(a3, tgt);
      while (!__all(ok)) {
        __builtin_amdgcn_s_sleep(1);
        ld_pkt3_wait(cbA + off1, cbA + off2, cbA + off3, a1, a2, a3);
        ok = PKT_OK(a1, tgt) && PKT_OK(a2, tgt) && PKT_OK(a3, tgt);
      }
    }
    {
      union { u64 u; _Float16 h[4]; } w1, w2, w3;
      w1.u = ((u64)a1[1] << 32) | a1[0];
      w2.u = ((u64)a2[1] << 32) | a2[0];
      w3.u = ((u64)a3[1] << 32) | a3[0];
#pragma unroll
      for (int r = 0; r < 4; ++r) {
        act[0][cr + r][192 + q1 * 64 + sblk * 16 + cc] = w1.h[r];
        act[0][cr + r][192 + q2 * 64 + sblk * 16 + cc] = w2.h[r];
        act[0][cr + r][192 + q3 * 64 + sblk * 16 + cc] = w3.h[r];
      }
    }
    SB();
    asm volatile("s_waitcnt vmcnt(0)" : "+v"(b1), "+v"(b2), "+v"(b3) :: "memory");
    SB();
    {
      int ok = PKT_OK(b1, tgt) && PKT_OK(b2, tgt) && PKT_OK(b3, tgt);
      while (!__all(ok)) {
        __builtin_amdgcn_s_sleep(1);
        ld_pkt3_wait(cbB + off1, cbB + off2, cbB + off3, b1, b2, b3);
        ok = PKT_OK(b1, tgt) && PKT_OK(b2, tgt) && PKT_OK(b3, tgt);
      }
    }
    {
      union { u64 u; _Float16 h[4]; } w1, w2, w3;
      w1.u = ((u64)b1[1] << 32) | b1[0];
      w2.u = ((u64)b2[1] << 32) | b2[0];
      w3.u = ((u64)b3[1] << 32) | b3[0];
#pragma unroll
      for (int r = 0; r < 4; ++r) {
        act[1][cr + r][192 + q1 * 64 + sblk * 16 + cc] = w1.h[r];
        act[1][cr + r][192 + q2 * 64 + sblk * 16 + cc] = w2.h[r];
        act[1][cr + r][192 + q3 * 64 + sblk * 16 + cc] = w3.h[r];
      }
    }
    __syncthreads();

#pragma unroll
    for (int kk = 0; kk < 8; ++kk) {
      if (kk == fk0 || kk == fk0 + 1) continue;
      half8 af = *(const half8*)&act[0][n][192 + kk * 32 + quad * 8];
      YA = mfma16(af, wfc[kk], YA);
    }
#pragma unroll
    for (int kk = 0; kk < 8; ++kk) {
      if (kk == fk0 || kk == fk0 + 1) continue;
      half8 af = *(const half8*)&act[1][n][192 + kk * 32 + quad * 8];
      YB = mfma16(af, wfc[kk], YB);
    }
#pragma unroll
    for (int r = 0; r < 4; ++r) {
      out[(size_t)(b0A + quad * 4 + r) * 64 + wv * 16 + n] = tanh_fast(YA[r] + fcb);
      out[(size_t)(b0B + quad * 4 + r) * 64 + wv * 16 + n] = tanh_fast(YB[r] + fcb);
    }
  }
}

extern "C" void kernel_launch(void* const* d_in, const int* in_sizes, int n_in,
                              void* d_out, int out_size, void* d_ws, size_t ws_size,
                              hipStream_t stream) {
  hipMemsetAsync(d_ws, 0, 262144, stream);  // both parities: epoch 0 + h(0)=0, XOR-valid
  jordan_rnn<<<dim3(16), dim3(256), 0, stream>>>(
      (const float*)d_in[0], (const float*)d_in[1], (const float*)d_in[2],
      (const float*)d_in[3], (const float*)d_in[4], (const float*)d_in[5],
      (const float*)d_in[6], (float*)d_out, (unsigned char*)d_ws);
}